// Round 12
// baseline (110.855 us; speedup 1.0000x reference)
//
#include <hip/hip_runtime.h>
#include <math.h>

#define BLOCK 256
#define NW (BLOCK / 64)
#define TILE (BLOCK * 2)   // 512 elements per tile; each thread owns 2 adjacent

typedef float f32x4 __attribute__((ext_vector_type(4)));

__device__ __forceinline__ float sp(float x) {
    // softplus: max(x,0) + log(1 + exp(-|x|)) — fast intrinsics, huge error budget
    return fmaxf(x, 0.0f) + __logf(1.0f + __expf(-fabsf(x)));
}

// Wave64 inclusive scan (add) on the VALU via DPP (verified rounds 7-11).
__device__ __forceinline__ float wave_scan_f32(float s) {
    s += __int_as_float(__builtin_amdgcn_update_dpp(0, __float_as_int(s), 0x111, 0xf, 0xf, false));
    s += __int_as_float(__builtin_amdgcn_update_dpp(0, __float_as_int(s), 0x112, 0xf, 0xf, false));
    s += __int_as_float(__builtin_amdgcn_update_dpp(0, __float_as_int(s), 0x114, 0xf, 0xf, false));
    s += __int_as_float(__builtin_amdgcn_update_dpp(0, __float_as_int(s), 0x118, 0xf, 0xf, false));
    s += __int_as_float(__builtin_amdgcn_update_dpp(0, __float_as_int(s), 0x142, 0xa, 0xf, false));
    s += __int_as_float(__builtin_amdgcn_update_dpp(0, __float_as_int(s), 0x143, 0xc, 0xf, false));
    return s;
}

// Barrier waiting only on LDS ops (global prefetches stay in flight).
__device__ __forceinline__ void lds_barrier() {
    asm volatile("s_waitcnt lgkmcnt(0)\n\ts_barrier" ::: "memory");
}

__global__ __launch_bounds__(BLOCK, 8) void socnet_kernel(
    const f32x4* __restrict__ X,      // (N, L) of 4-ch float4
    const float*  __restrict__ SC,    // (N, 4)
    const float*  __restrict__ wi1, const float* __restrict__ bi1,
    const float*  __restrict__ wi2, const float* __restrict__ bi2,
    const float*  __restrict__ we1, const float* __restrict__ be1,
    const float*  __restrict__ we2, const float* __restrict__ be2,
    f32x4* __restrict__ Y, int L)
{
    const int n    = blockIdx.x;
    const int t    = threadIdx.x;
    const int wid  = t >> 6;

    const size_t rowoff = (size_t)n * (size_t)L;
    const f32x4* Xr = X + rowoff;
    f32x4*       Yr = Y + rowoff;

    // eta MLP weights (broadcast scalars)
    const float W10 = we1[0], W11 = we1[1], B1 = be1[0];
    const float W2  = we2[0], B2e = be2[0];

    // per-row scalars
    const float Q    = SC[n * 4 + 0];
    const float eta0 = SC[n * 4 + 1];
    const float R    = SC[n * 4 + 2];
    const float S3   = SC[n * 4 + 3];
    const float inv  = eta0 / (3600.0f * Q);

    // soc_init from X[n,0,:]
    const f32x4 x0 = Xr[0];
    const float h0 = sp(wi1[0] * x0.y + wi1[1] * x0.z + wi1[2] * x0.w + wi1[3] * R + bi1[0]);
    const float soc = S3 * (1.0f + (wi2[0] * h0 + bi2[0]));

    // s_obsE[b][i] = obs(I,T,U,de) of EVEN element (tile*512 + 2i), i in [0,256]
    // (entry 256 = next tile's element 0). Odd elements' neighbors only.
    __shared__ f32x4 s_obsE[2][BLOCK + 1];
    __shared__ f32x4 s_wsum[2][NW];

    f32x4 carry = (f32x4)(0.0f);

    const int ntiles = L / TILE;  // 8
    const int Lm1 = L - 1;

    // pipeline: stage0 = tile j (current), stage1 = tile j+1; stage2 issued in-loop
    const int pe = 2 * t;
    f32x4 xE0 = Xr[pe];
    f32x4 xO0 = Xr[pe + 1];
    int i1e = pe + TILE;     if (i1e > Lm1) i1e = Lm1;
    int i1o = pe + TILE + 1; if (i1o > Lm1) i1o = Lm1;
    f32x4 xE1 = Xr[i1e];
    f32x4 xO1 = Xr[i1o];

    float deE0 = W2 * sp(W10 * xE0.y + W11 * xE0.z + B1) + B2e;

    // prologue: fill tile-0 neighbor table
    {
        f32x4 ob; ob.x = xE0.y; ob.y = xE0.z; ob.z = xE0.w; ob.w = deE0;
        s_obsE[0][t] = ob;
        if (t == 0) {  // entry 256 = element TILE (tile 1, elem 0) from xE1 lane 0
            const float d = W2 * sp(W10 * xE1.y + W11 * xE1.z + B1) + B2e;
            f32x4 ob2; ob2.x = xE1.y; ob2.y = xE1.z; ob2.z = xE1.w; ob2.w = d;
            s_obsE[0][BLOCK] = ob2;
        }
    }
    lds_barrier();

    for (int j = 0; j < ntiles; ++j) {
        // prefetch stage 2 (tile j+2); stays in flight across lds_barrier
        int i2e = (j + 2) * TILE + pe;     if (i2e > Lm1) i2e = Lm1;
        int i2o = i2e + 1;                 if (i2o > Lm1) i2o = Lm1;
        const f32x4 xE2 = Xr[i2e];
        const f32x4 xO2 = Xr[i2o];

        // neighbor of own ODD element = table entry t+1 (written last tile)
        const f32x4 nb = s_obsE[j & 1][t + 1];

        // ahead-compute next tile's even de; fill table buf[(j+1)&1]
        const float deE1 = W2 * sp(W10 * xE1.y + W11 * xE1.z + B1) + B2e;
        {
            f32x4 ob; ob.x = xE1.y; ob.y = xE1.z; ob.z = xE1.w; ob.w = deE1;
            s_obsE[(j + 1) & 1][t] = ob;
            if (t == 0) {  // entry 256 = tile j+2's element 0, from xE2 lane 0
                const float d2 = W2 * sp(W10 * xE2.y + W11 * xE2.z + B1) + B2e;
                f32x4 ob2; ob2.x = xE2.y; ob2.y = xE2.z; ob2.z = xE2.w; ob2.w = d2;
                s_obsE[(j + 1) & 1][BLOCK] = ob2;
            }
        }

        // own odd de (1 sp chain; even's was ahead-computed => 1 sp per element)
        const float deO0 = W2 * sp(W10 * xO0.y + W11 * xO0.z + B1) + B2e;

        // incE (neighbor = own odd, in-register), incO (neighbor = table)
        const float dyE = inv * (1.0f + deE0) * xE0.y;
        f32x4 incE;
        incE.x = (xO0.y - xE0.y) * dyE;
        incE.y = (xO0.z - xE0.z) * dyE;
        incE.z = (xO0.w - xE0.w) * dyE;
        incE.w = (deO0  - deE0)  * dyE;

        const float dyO = inv * (1.0f + deO0) * xO0.y;
        f32x4 incO;
        incO.x = (nb.x - xO0.y) * dyO;
        incO.y = (nb.y - xO0.z) * dyO;
        incO.z = (nb.z - xO0.w) * dyO;
        incO.w = (nb.w - deO0)  * dyO;

        // scan over PAIR sums: 24 DPP-adds cover 2 elements
        const f32x4 pair = incE + incO;
        f32x4 scn;
        scn.x = wave_scan_f32(pair.x);
        scn.y = wave_scan_f32(pair.y);
        scn.z = wave_scan_f32(pair.z);
        scn.w = wave_scan_f32(pair.w);

        if ((t & 63) == 63) s_wsum[j & 1][wid] = scn;
        lds_barrier();  // fences s_obsE handoff + s_wsum publication

        // exclusive prefix (pairs) = carry + prev-wave totals + (scn - pair)
        f32x4 excl = carry + scn - pair;
        #pragma unroll
        for (int w = 0; w < NW; ++w) {
            const f32x4 ws = s_wsum[j & 1][w];
            if (w < wid) excl += ws;
            carry += ws;
        }

        // y[2t] = soc + excl;  y[2t+1] = y[2t] + incE
        const f32x4 yE = excl + (f32x4)(soc);
        const f32x4 yO = yE + incE;
        f32x4* dst = &Yr[(size_t)j * TILE + pe];
        __builtin_nontemporal_store(yE, dst);
        __builtin_nontemporal_store(yO, dst + 1);

        // rotate pipeline
        xE0 = xE1; xO0 = xO1; deE0 = deE1;
        xE1 = xE2; xO1 = xO2;
    }
}

extern "C" void kernel_launch(void* const* d_in, const int* in_sizes, int n_in,
                              void* d_out, int out_size, void* d_ws, size_t ws_size,
                              hipStream_t stream) {
    const f32x4* X   = (const f32x4*)d_in[0];
    const float* SC  = (const float*)d_in[1];
    const float* wi1 = (const float*)d_in[2];
    const float* bi1 = (const float*)d_in[3];
    const float* wi2 = (const float*)d_in[4];
    const float* bi2 = (const float*)d_in[5];
    const float* we1 = (const float*)d_in[6];
    const float* be1 = (const float*)d_in[7];
    const float* we2 = (const float*)d_in[8];
    const float* be2 = (const float*)d_in[9];
    f32x4* Y = (f32x4*)d_out;

    const int N = in_sizes[1] / 4;           // SC is (N,4)
    const int L = in_sizes[0] / (4 * N);     // X is (N,L,4); L = TILE * ntiles

    socnet_kernel<<<N, BLOCK, 0, stream>>>(X, SC, wi1, bi1, wi2, bi2,
                                           we1, be1, we2, be2, Y, L);
}

// Round 13
// 90.643 us; speedup vs baseline: 1.2230x; 1.2230x over previous
//
#include <hip/hip_runtime.h>
#include <math.h>

#define BLOCK 256
#define NW (BLOCK / 64)
#define TILE (BLOCK * 2)   // 512 elements per tile; each thread owns 2 adjacent

typedef float f32x4 __attribute__((ext_vector_type(4)));

__device__ __forceinline__ float sp(float x) {
    // softplus: max(x,0) + log(1 + exp(-|x|)) — fast intrinsics, huge error budget
    return fmaxf(x, 0.0f) + __logf(1.0f + __expf(-fabsf(x)));
}

// Wave64 inclusive scan (add) on the VALU via DPP (verified rounds 7-12).
__device__ __forceinline__ float wave_scan_f32(float s) {
    s += __int_as_float(__builtin_amdgcn_update_dpp(0, __float_as_int(s), 0x111, 0xf, 0xf, false));
    s += __int_as_float(__builtin_amdgcn_update_dpp(0, __float_as_int(s), 0x112, 0xf, 0xf, false));
    s += __int_as_float(__builtin_amdgcn_update_dpp(0, __float_as_int(s), 0x114, 0xf, 0xf, false));
    s += __int_as_float(__builtin_amdgcn_update_dpp(0, __float_as_int(s), 0x118, 0xf, 0xf, false));
    s += __int_as_float(__builtin_amdgcn_update_dpp(0, __float_as_int(s), 0x142, 0xa, 0xf, false));
    s += __int_as_float(__builtin_amdgcn_update_dpp(0, __float_as_int(s), 0x143, 0xc, 0xf, false));
    return s;
}

// Barrier waiting only on LDS ops (global prefetches stay in flight).
__device__ __forceinline__ void lds_barrier() {
    asm volatile("s_waitcnt lgkmcnt(0)\n\ts_barrier" ::: "memory");
}

__global__ __launch_bounds__(BLOCK, 8) void socnet_kernel(
    const f32x4* __restrict__ X,      // (N, L) of 4-ch float4
    const float*  __restrict__ SC,    // (N, 4)
    const float*  __restrict__ wi1, const float* __restrict__ bi1,
    const float*  __restrict__ wi2, const float* __restrict__ bi2,
    const float*  __restrict__ we1, const float* __restrict__ be1,
    const float*  __restrict__ we2, const float* __restrict__ be2,
    f32x4* __restrict__ Y, int L)
{
    const int n    = blockIdx.x;
    const int t    = threadIdx.x;
    const int wid  = t >> 6;

    const size_t rowoff = (size_t)n * (size_t)L;
    const f32x4* Xr = X + rowoff;
    f32x4*       Yr = Y + rowoff;

    // eta MLP weights (broadcast scalars)
    const float W10 = we1[0], W11 = we1[1], B1 = be1[0];
    const float W2  = we2[0], B2e = be2[0];

    // per-row scalars
    const float Q    = SC[n * 4 + 0];
    const float eta0 = SC[n * 4 + 1];
    const float R    = SC[n * 4 + 2];
    const float S3   = SC[n * 4 + 3];
    const float inv  = eta0 / (3600.0f * Q);

    // soc_init from X[n,0,:]
    const f32x4 x0 = Xr[0];
    const float h0 = sp(wi1[0] * x0.y + wi1[1] * x0.z + wi1[2] * x0.w + wi1[3] * R + bi1[0]);
    const float soc = S3 * (1.0f + (wi2[0] * h0 + bi2[0]));

    // s_obsE[b][i] = obs(I,T,U,de) of EVEN element (tile*512 + 2i), i in [0,256]
    __shared__ f32x4 s_obsE[2][BLOCK + 1];
    __shared__ f32x4 s_wsum[2][NW];
    // y-staging: deinterleave so both NT store instructions are lane-contiguous.
    __shared__ f32x4 s_y[TILE];

    f32x4 carry = (f32x4)(0.0f);

    const int ntiles = L / TILE;  // 8
    const int Lm1 = L - 1;

    // pipeline: stage0 = tile j (current), stage1 = tile j+1; stage2 issued in-loop
    const int pe = 2 * t;
    f32x4 xE0 = Xr[pe];
    f32x4 xO0 = Xr[pe + 1];
    int i1e = pe + TILE;     if (i1e > Lm1) i1e = Lm1;
    int i1o = pe + TILE + 1; if (i1o > Lm1) i1o = Lm1;
    f32x4 xE1 = Xr[i1e];
    f32x4 xO1 = Xr[i1o];

    float deE0 = W2 * sp(W10 * xE0.y + W11 * xE0.z + B1) + B2e;

    // prologue: fill tile-0 neighbor table
    {
        f32x4 ob; ob.x = xE0.y; ob.y = xE0.z; ob.z = xE0.w; ob.w = deE0;
        s_obsE[0][t] = ob;
        if (t == 0) {
            const float d = W2 * sp(W10 * xE1.y + W11 * xE1.z + B1) + B2e;
            f32x4 ob2; ob2.x = xE1.y; ob2.y = xE1.z; ob2.z = xE1.w; ob2.w = d;
            s_obsE[0][BLOCK] = ob2;
        }
    }
    lds_barrier();

    for (int j = 0; j < ntiles; ++j) {
        // prefetch stage 2 (tile j+2); stays in flight across lds_barrier
        int i2e = (j + 2) * TILE + pe;     if (i2e > Lm1) i2e = Lm1;
        int i2o = i2e + 1;                 if (i2o > Lm1) i2o = Lm1;
        const f32x4 xE2 = Xr[i2e];
        const f32x4 xO2 = Xr[i2o];

        // neighbor of own ODD element = table entry t+1 (written last tile)
        const f32x4 nb = s_obsE[j & 1][t + 1];

        // ahead-compute next tile's even de; fill table buf[(j+1)&1]
        const float deE1 = W2 * sp(W10 * xE1.y + W11 * xE1.z + B1) + B2e;
        {
            f32x4 ob; ob.x = xE1.y; ob.y = xE1.z; ob.z = xE1.w; ob.w = deE1;
            s_obsE[(j + 1) & 1][t] = ob;
            if (t == 0) {
                const float d2 = W2 * sp(W10 * xE2.y + W11 * xE2.z + B1) + B2e;
                f32x4 ob2; ob2.x = xE2.y; ob2.y = xE2.z; ob2.z = xE2.w; ob2.w = d2;
                s_obsE[(j + 1) & 1][BLOCK] = ob2;
            }
        }

        // own odd de (1 sp chain; even's was ahead-computed => 1 sp per element)
        const float deO0 = W2 * sp(W10 * xO0.y + W11 * xO0.z + B1) + B2e;

        // incE (neighbor = own odd, in-register), incO (neighbor = table)
        const float dyE = inv * (1.0f + deE0) * xE0.y;
        f32x4 incE;
        incE.x = (xO0.y - xE0.y) * dyE;
        incE.y = (xO0.z - xE0.z) * dyE;
        incE.z = (xO0.w - xE0.w) * dyE;
        incE.w = (deO0  - deE0)  * dyE;

        const float dyO = inv * (1.0f + deO0) * xO0.y;
        f32x4 incO;
        incO.x = (nb.x - xO0.y) * dyO;
        incO.y = (nb.y - xO0.z) * dyO;
        incO.z = (nb.z - xO0.w) * dyO;
        incO.w = (nb.w - deO0)  * dyO;

        // scan over PAIR sums: 24 DPP-adds cover 2 elements
        const f32x4 pair = incE + incO;
        f32x4 scn;
        scn.x = wave_scan_f32(pair.x);
        scn.y = wave_scan_f32(pair.y);
        scn.z = wave_scan_f32(pair.z);
        scn.w = wave_scan_f32(pair.w);

        if ((t & 63) == 63) s_wsum[j & 1][wid] = scn;
        lds_barrier();  // fences s_obsE handoff + s_wsum publication

        // exclusive prefix (pairs) = carry + prev-wave totals + (scn - pair)
        f32x4 excl = carry + scn - pair;
        #pragma unroll
        for (int w = 0; w < NW; ++w) {
            const f32x4 ws = s_wsum[j & 1][w];
            if (w < wid) excl += ws;
            carry += ws;
        }

        // y[2t] = soc + excl; y[2t+1] = y[2t] + incE — stage via LDS (deinterleave)
        const f32x4 yE = excl + (f32x4)(soc);
        const f32x4 yO = yE + incE;
        s_y[t]         = yE;   // slot e/2       for even e=2t
        s_y[BLOCK + t] = yO;   // slot 256 + e/2 for odd  e=2t+1
        lds_barrier();

        // thread t emits elements t and t+256 — both store instrs lane-contiguous
        const int r0 = (t & 1) * BLOCK + (t >> 1);
        const f32x4 ya = s_y[r0];
        const f32x4 yb = s_y[r0 + BLOCK / 2];
        f32x4* dst = &Yr[(size_t)j * TILE + t];
        __builtin_nontemporal_store(ya, dst);
        __builtin_nontemporal_store(yb, dst + BLOCK);

        // rotate pipeline
        xE0 = xE1; xO0 = xO1; deE0 = deE1;
        xE1 = xE2; xO1 = xO2;
    }
}

extern "C" void kernel_launch(void* const* d_in, const int* in_sizes, int n_in,
                              void* d_out, int out_size, void* d_ws, size_t ws_size,
                              hipStream_t stream) {
    const f32x4* X   = (const f32x4*)d_in[0];
    const float* SC  = (const float*)d_in[1];
    const float* wi1 = (const float*)d_in[2];
    const float* bi1 = (const float*)d_in[3];
    const float* wi2 = (const float*)d_in[4];
    const float* bi2 = (const float*)d_in[5];
    const float* we1 = (const float*)d_in[6];
    const float* be1 = (const float*)d_in[7];
    const float* we2 = (const float*)d_in[8];
    const float* be2 = (const float*)d_in[9];
    f32x4* Y = (f32x4*)d_out;

    const int N = in_sizes[1] / 4;           // SC is (N,4)
    const int L = in_sizes[0] / (4 * N);     // X is (N,L,4); L = TILE * ntiles

    socnet_kernel<<<N, BLOCK, 0, stream>>>(X, SC, wi1, bi1, wi2, bi2,
                                           we1, be1, we2, be2, Y, L);
}